// Round 7
// baseline (638.232 us; speedup 1.0000x reference)
//
#include <hip/hip_runtime.h>
#include <stdint.h>

// ---------- types ----------
typedef __attribute__((ext_vector_type(4))) uint16_t u16x4;
typedef __attribute__((ext_vector_type(8))) uint16_t u16x8;
typedef __attribute__((ext_vector_type(8))) __bf16  bf16x8;
typedef __attribute__((ext_vector_type(4))) float   f32x4;

__device__ __forceinline__ uint16_t f2bf(float f) {
  uint32_t x = __float_as_uint(f);
  x += 0x7fffu + ((x >> 16) & 1u);   // RNE
  return (uint16_t)(x >> 16);
}
__device__ __forceinline__ f32x4 mfma32(bf16x8 a, bf16x8 b, f32x4 c) {
  return __builtin_amdgcn_mfma_f32_16x16x32_bf16(a, b, c, 0, 0, 0);
}
// async global->LDS, 16B/lane. LDS dest = wave-uniform base + lane*16.
__device__ __forceinline__ void gld16(const uint16_t* g, uint16_t* s) {
  __builtin_amdgcn_global_load_lds(
      (const __attribute__((address_space(1))) void*)g,
      (__attribute__((address_space(3))) void*)s, 16, 0, 0);
}
#define SB0() __builtin_amdgcn_sched_barrier(0)

// Problem: B=2, frames=16, spatial=1024, hidden=1024, nh=16, hd=64.
// Inputs/outputs are FLOAT32 (per reference). Internals bf16 for MFMA.

// ---------- 0) weights f32 -> bf16 (w_qkv 3072x1024 then w_out 1024x1024) ----------
__global__ __launch_bounds__(256)
void conv_w(const float* __restrict__ wq, const float* __restrict__ wo,
            uint16_t* __restrict__ dst) {
  int i = blockIdx.x * 256 + threadIdx.x;        // vec4 idx, 1048576 total
  float4 v = (i < 786432) ? ((const float4*)wq)[i]
                          : ((const float4*)wo)[i - 786432];
  u16x4 o;
  o[0] = f2bf(v.x); o[1] = f2bf(v.y); o[2] = f2bf(v.z); o[3] = f2bf(v.w);
  ((u16x4*)dst)[i] = o;
}

// ---------- 1) LayerNorm (f32 in) + gather into xt_chunk[nl*16+t][d] (bf16) ----------
__global__ __launch_bounds__(256)
void ln_chunk(const float* __restrict__ x, const float* __restrict__ gw,
              const float* __restrict__ bw, uint16_t* __restrict__ xt, int c0) {
  const int wv = threadIdx.x >> 6, lane = threadIdx.x & 63;
  const int r = blockIdx.x * 4 + wv;        // local xt row: nl*16 + t
  const int nl = r >> 4, t = r & 15;
  const int n = c0 + nl, b = n >> 10, sp = n & 1023;
  const float* xr = x + ((size_t)b * 16384 + (size_t)t * 1024 + sp) * 1024;
  float4 v[4];
#pragma unroll
  for (int c = 0; c < 4; ++c) v[c] = ((const float4*)xr)[c * 64 + lane];
  float s = 0.f, ss = 0.f;
#pragma unroll
  for (int c = 0; c < 4; ++c) {
    s  += v[c].x + v[c].y + v[c].z + v[c].w;
    ss += v[c].x * v[c].x + v[c].y * v[c].y + v[c].z * v[c].z + v[c].w * v[c].w;
  }
#pragma unroll
  for (int o = 32; o > 0; o >>= 1) { s += __shfl_xor(s, o); ss += __shfl_xor(ss, o); }
  const float mu = s * (1.f / 1024.f);
  const float var = ss * (1.f / 1024.f) - mu * mu;
  const float rs = rsqrtf(var + 1e-5f);
  uint16_t* orow = xt + (size_t)r * 1024;
#pragma unroll
  for (int c = 0; c < 4; ++c) {
    float4 g = ((const float4*)gw)[c * 64 + lane];
    float4 be = ((const float4*)bw)[c * 64 + lane];
    u16x4 o;
    o[0] = f2bf((v[c].x - mu) * rs * g.x + be.x);
    o[1] = f2bf((v[c].y - mu) * rs * g.y + be.y);
    o[2] = f2bf((v[c].z - mu) * rs * g.z + be.z);
    o[3] = f2bf((v[c].w - mu) * rs * g.w + be.w);
    ((u16x4*)orow)[c * 64 + lane] = o;
  }
}

// ---------- 2&4) C = A * B^T GEMM (bf16 in), K=1024 ----------
// BM=BN=256, BK=64, 8 waves (2M x 4N of 128x64 wave-tiles), 512 threads.
// 8-PHASE schedule (m201 port): per K-tile, 4 phases of 16 MFMA each,
// phase = {ds_read own subtile (4-8 reads); p0: issue 8 stage loads kt+1;
// s_barrier; (lgkm waits by compiler); setprio(1); 16 MFMA; setprio(0);
// s_barrier}.  Tile-end: own-wave vmcnt(0) BEFORE the final barrier (loads
// were issued 3 phases earlier -> nearly free; barrier publishes all waves'
// staging).  All motion pinned with sched_barrier(0).  b-frags read once
// per ko, held across the phase pair (24 ds_read_b128/tile/wave).
// LDS layout: LDS[row][c] = global[row][c ^ (row&7)] chunk-XOR via
// pre-swizzled GLOBAL source (global_load_lds writes linearly); read side
// kchunk XOR unchanged (verified since round 2).
// EPI==1: qkv epilogue (RoPE on q,k; q scaled 0.125) -> C0=q,C1=k,C2=v
// as [nl][h][t][d].  EPI==0: FLOAT32 to F0, local row l -> t=l>>lgc,
// nl=l&(chunkN-1), grow = b*16384 + t*1024 + sp.
template <int EPI>
__global__ __launch_bounds__(512)
void gemm_bt(const uint16_t* __restrict__ A, const uint16_t* __restrict__ B,
             uint16_t* __restrict__ C0, uint16_t* __restrict__ C1,
             uint16_t* __restrict__ C2, float* __restrict__ F0, int c0, int lgc) {
  __shared__ __align__(16) uint16_t As[2][16384];   // 256 rows x 64, chunk-swizzled
  __shared__ __align__(16) uint16_t Bs[2][16384];
  const int tid = threadIdx.x, lane = tid & 63, w = tid >> 6;   // w: 0..7
  const int bn = blockIdx.x, bm = blockIdx.y;
  const int srow = lane >> 3;               // 0..7
  const int schunk = (lane & 7) ^ srow;     // pre-swizzled global source chunk
  const uint16_t* ga = A + (size_t)(bm * 256 + w * 32 + srow) * 1024 + schunk * 8;
  const uint16_t* gb = B + (size_t)(bn * 256 + w * 32 + srow) * 1024 + schunk * 8;
  const int sOff = w * 2048;                // wave-uniform LDS base (32 rows x 64)
  const int wm = w >> 2, wn = w & 3;        // 2M x 4N wave grid
  const int fr = lane & 15, quad = lane >> 4;
  f32x4 acc[8][4];
#pragma unroll
  for (int i = 0; i < 8; ++i)
#pragma unroll
    for (int j = 0; j < 4; ++j) acc[i][j] = (f32x4){0.f, 0.f, 0.f, 0.f};

  // prologue: stage K-tile 0 into buffer 0 (8 loads/wave), drain, publish.
#pragma unroll
  for (int i = 0; i < 4; ++i) {
    gld16(ga + (size_t)i * 8192, &As[0][sOff + i * 512]);
    gld16(gb + (size_t)i * 8192, &Bs[0][sOff + i * 512]);
  }
  ga += 64; gb += 64;
  SB0();
  asm volatile("s_waitcnt vmcnt(0)" ::: "memory");
  SB0();
  __builtin_amdgcn_s_barrier();
  SB0();

  for (int kt = 0; kt < 16; ++kt) {
    const int cur = kt & 1;
    const uint16_t* as = As[cur];
    const uint16_t* bs = Bs[cur];
#pragma unroll
    for (int ko = 0; ko < 2; ++ko) {
      const int kchunk = ((ko * 4 + quad) ^ (fr & 7)) * 8;
      bf16x8 b[4];
#pragma unroll
      for (int tn = 0; tn < 4; ++tn)
        b[tn] = *(const bf16x8*)&bs[(wn * 64 + tn * 16 + fr) * 64 + kchunk];
#pragma unroll
      for (int h = 0; h < 2; ++h) {
        // ---- phase (ko,h): read own a-subtile ----
        bf16x8 a[4];
#pragma unroll
        for (int t = 0; t < 4; ++t)
          a[t] = *(const bf16x8*)&as[(wm * 128 + (h * 4 + t) * 16 + fr) * 64 + kchunk];
        if (ko == 0 && h == 0 && kt < 15) {   // stage kt+1 during phase 0
#pragma unroll
          for (int i = 0; i < 4; ++i) {
            gld16(ga + (size_t)i * 8192, &As[cur ^ 1][sOff + i * 512]);
            gld16(gb + (size_t)i * 8192, &Bs[cur ^ 1][sOff + i * 512]);
          }
          ga += 64; gb += 64;
        }
        SB0();
        __builtin_amdgcn_s_barrier();
        SB0();
        __builtin_amdgcn_s_setprio(1);
#pragma unroll
        for (int t = 0; t < 4; ++t)
#pragma unroll
          for (int tn = 0; tn < 4; ++tn)
            acc[h * 4 + t][tn] = mfma32(a[t], b[tn], acc[h * 4 + t][tn]);
        __builtin_amdgcn_s_setprio(0);
        SB0();
        if (ko == 1 && h == 1) {              // tile end: own loads resident,
          asm volatile("s_waitcnt vmcnt(0)" ::: "memory");  // then publish
          SB0();
        }
        __builtin_amdgcn_s_barrier();
        SB0();
      }
    }
  }

  // C/D layout: row = quad*4+r, col = fr (verified m89/m91)
  if (EPI == 0) {
#pragma unroll
    for (int tm = 0; tm < 8; ++tm) {
#pragma unroll
      for (int tn = 0; tn < 4; ++tn) {
        int colg = bn * 256 + wn * 64 + tn * 16 + fr;
#pragma unroll
        for (int r = 0; r < 4; ++r) {
          int l = bm * 256 + wm * 128 + tm * 16 + quad * 4 + r;   // local row
          int t = l >> lgc, nl = l & ((1 << lgc) - 1);
          int n = c0 + nl, b = n >> 10, sp = n & 1023;
          size_t grow = (size_t)b * 16384 + (size_t)t * 1024 + sp;
          F0[grow * 1024 + colg] = acc[tm][tn][r];
        }
      }
    }
  } else {
    // RoPE tables built AFTER the K-loop, reusing As/Bs LDS.
    float* cosT = (float*)As;    // [t][i], t<16, i<32 (512 floats = 2KB)
    float* sinT = (float*)&Bs[0][0];
    __syncthreads();             // all waves done reading As/Bs (full drain ok, once)
    if (tid < 512) {
      int t = tid >> 5, i = tid & 31;
      float ang = (float)t * expf(-(float)i * 0.28782313662425574f); // 10000^(-i/32)
      cosT[tid] = cosf(ang);
      sinT[tid] = sinf(ang);
    }
    __syncthreads();
    // wave's 64-col span = one (which, head); local row m = nl*16 + t
    const int e0 = bn * 256 + wn * 64;
    const int which = e0 >> 10;
    const int h = (e0 >> 6) & 15;
    const int n_base = bm * 16 + wm * 8;   // local nl base (tm block = one nl)
    if (which == 2) {                      // v: plain scatter to [nl][h][t][d]
#pragma unroll
      for (int tm = 0; tm < 8; ++tm) {
        size_t base = ((size_t)(n_base + tm) * 16 + h) * 1024 + (size_t)(quad * 4) * 64;
#pragma unroll
        for (int tn = 0; tn < 4; ++tn) {
          int d = tn * 16 + fr;
#pragma unroll
          for (int r = 0; r < 4; ++r)
            C2[base + (size_t)r * 64 + d] = f2bf(acc[tm][tn][r]);
        }
      }
    } else {                               // q,k: RoPE (d pairs with d+32)
      uint16_t* dst = (which == 0) ? C0 : C1;
      const float sc = (which == 0) ? 0.125f : 1.0f;  // fold hd^-0.5 into q
#pragma unroll
      for (int tm = 0; tm < 8; ++tm) {
        size_t base0 = ((size_t)(n_base + tm) * 16 + h) * 1024;
#pragma unroll
        for (int tn2 = 0; tn2 < 2; ++tn2) {
          int d1 = tn2 * 16 + fr;          // < 32; pairs with tile tn2+2
#pragma unroll
          for (int r = 0; r < 4; ++r) {
            int t = quad * 4 + r;
            float c = cosT[t * 32 + d1], s = sinT[t * 32 + d1];
            float x1 = acc[tm][tn2][r], x2 = acc[tm][tn2 + 2][r];
            dst[base0 + (size_t)t * 64 + d1]      = f2bf((x1 * c - x2 * s) * sc);
            dst[base0 + (size_t)t * 64 + d1 + 32] = f2bf((x2 * c + x1 * s) * sc);
          }
        }
      }
    }
  }
}

// ---------- 3) causal attention over T=16, one wave per local (nl,h) ----------
// writes o_chunk[t*chunkN + nl][h*64+d] (bf16; reuses the dead xt buffer)
__global__ __launch_bounds__(256)
void attn_chunk(const uint16_t* __restrict__ q, const uint16_t* __restrict__ k,
                const uint16_t* __restrict__ v, uint16_t* __restrict__ out,
                int chunkN) {
  __shared__ float sPT[4][16][17];
  const int wv = threadIdx.x >> 6, lane = threadIdx.x & 63;
  const int pair = blockIdx.x * 4 + wv;     // nl*16 + h
  const int nl = pair >> 4, h = pair & 15;
  const uint16_t* qb = q + (size_t)pair * 1024;   // [t][d] 16x64
  const uint16_t* kb = k + (size_t)pair * 1024;
  const uint16_t* vb = v + (size_t)pair * 1024;
  const int col = lane & 15, quad = lane >> 4;
  const int ro = col * 64 + quad * 8;
  // S^T = K * Q^T : A[m=tk][kd=d] from K rows, B[n=tq][kd=d] from Q rows
  bf16x8 ka0 = *(const bf16x8*)(kb + ro);
  bf16x8 ka1 = *(const bf16x8*)(kb + ro + 32);
  bf16x8 qa0 = *(const bf16x8*)(qb + ro);
  bf16x8 qa1 = *(const bf16x8*)(qb + ro + 32);
  f32x4 s4 = (f32x4){0.f, 0.f, 0.f, 0.f};
  s4 = mfma32(ka0, qa0, s4);
  s4 = mfma32(ka1, qa1, s4);
  // lane holds S^T[tk=quad*4+r][tq=col]; softmax over tk
  float p[4];
  float mx = -3.0e38f;
#pragma unroll
  for (int r = 0; r < 4; ++r) {
    int tk = quad * 4 + r;
    p[r] = (tk <= col) ? s4[r] : -3.0e38f;  // causal mask (finite, no inf-inf)
    mx = fmaxf(mx, p[r]);
  }
  mx = fmaxf(mx, __shfl_xor(mx, 16));
  mx = fmaxf(mx, __shfl_xor(mx, 32));
  float sum = 0.f;
#pragma unroll
  for (int r = 0; r < 4; ++r) {
    p[r] = (p[r] <= -1.0e38f) ? 0.f : expf(p[r] - mx);
    sum += p[r];
  }
  sum += __shfl_xor(sum, 16);
  sum += __shfl_xor(sum, 32);
  const float inv = 1.f / sum;
  // LDS round-trip: P^T(C-layout) -> P(A-layout)
#pragma unroll
  for (int r = 0; r < 4; ++r) sPT[wv][quad * 4 + r][col] = p[r] * inv;
  __syncthreads();
  bf16x8 pa;   // A[m=tq=col][kd=tk=quad*8+j], K-pad quads zeroed
#pragma unroll
  for (int j = 0; j < 8; ++j) {
    float pv = (quad < 2) ? sPT[wv][(quad * 8 + j) & 15][col] : 0.f;
    pa[j] = (__bf16)pv;
  }
  const __bf16* vbf = (const __bf16*)vb;
#pragma unroll
  for (int dt = 0; dt < 4; ++dt) {
    bf16x8 bv;    // B-frag[n=dt*16+col][kd=tk=quad*8+j] = V[tk][d]; pad zeroed
#pragma unroll
    for (int j = 0; j < 8; ++j) {
      int tk = (quad * 8 + j) & 15;
      __bf16 val = vbf[tk * 64 + dt * 16 + col];
      bv[j] = (quad < 2) ? val : (__bf16)0.f;
    }
    f32x4 o = (f32x4){0.f, 0.f, 0.f, 0.f};
    o = mfma32(pa, bv, o);
#pragma unroll
    for (int r = 0; r < 4; ++r) {    // o_chunk[t*chunkN+nl][h*64+d]
      int t = quad * 4 + r;
      out[((size_t)t * chunkN + nl) * 1024 + h * 64 + dt * 16 + col] = f2bf(o[r]);
    }
  }
}

// ---------- launch ----------
extern "C" void kernel_launch(void* const* d_in, const int* in_sizes, int n_in,
                              void* d_out, int out_size, void* d_ws, size_t ws_size,
                              hipStream_t stream) {
  const float* x     = (const float*)d_in[0];
  const float* w_qkv = (const float*)d_in[1];
  const float* w_out = (const float*)d_in[2];
  const float* gamma = (const float*)d_in[3];
  const float* beta  = (const float*)d_in[4];
  float* out = (float*)d_out;

  // ws: [w_qkv_bf 3145728 | w_out_bf 1048576] + per-chunk xt/q/k/v
  uint16_t* wqb = (uint16_t*)d_ws;
  uint16_t* wob = wqb + 3145728;
  uint16_t* base = wob + 1048576;
  const size_t wbytes = 4194304ull * 2;
  size_t avail = (ws_size > wbytes) ? ws_size - wbytes : 0;
  size_t chunkN = 2048;
  while (chunkN > 16 && chunkN * 131072ull > avail) chunkN >>= 1;  // >=16: BM=256 needs 16 nl/block
  int lgc = 31 - __builtin_clz((unsigned)chunkN);
  const int nch = (int)(2048 / chunkN);
  const size_t seg = chunkN * 16384;   // bf16 elems per buffer
  uint16_t* xt = base;                 // xt, later reused as attn output
  uint16_t* qb = xt + seg;
  uint16_t* kb = qb + seg;
  uint16_t* vb = kb + seg;

  conv_w<<<dim3(4096), dim3(256), 0, stream>>>(w_qkv, w_out, wqb);
  for (int c = 0; c < nch; ++c) {
    const int c0 = c * (int)chunkN;
    ln_chunk<<<dim3((uint32_t)chunkN * 4), dim3(256), 0, stream>>>(
        x, gamma, beta, xt, c0);
    gemm_bt<1><<<dim3(12, (uint32_t)chunkN / 16), dim3(512), 0, stream>>>(
        xt, wqb, qb, kb, vb, nullptr, 0, 0);
    attn_chunk<<<dim3((uint32_t)chunkN * 4), dim3(256), 0, stream>>>(
        qb, kb, vb, xt, (int)chunkN);
    gemm_bt<0><<<dim3(4, (uint32_t)chunkN / 16), dim3(512), 0, stream>>>(
        xt, wob, nullptr, nullptr, nullptr, out, c0, lgc);
  }
}